// Round 10
// baseline (25.454 us; speedup 1.0000x reference)
//
#include <hip/hip_runtime.h>
#include <hip/hip_bf16.h>

// Problem constants
#define L_CNT 128
#define R_CNT 1024
#define T_CNT 16
#define E_CNT 32

// rbf = exp(-((d-mu)/sigma)^2), sigma = -0.3125 -> 1/sigma^2 = 10.24
// exp2 domain: rbf_e(d) = exp2(-(d*SFAC - e*MUS)^2), MUS = SFAC*10/31.
constexpr float SFAC    = 3.8435917f;              // sqrt(10.24 * log2(e))
constexpr float MUS     = SFAC * (10.0f / 31.0f);  // 1.2398683
constexpr float INV_MUS = 1.0f / MUS;

#if defined(__has_builtin)
#  if __has_builtin(__builtin_amdgcn_exp2f)
#    define EXP2(x) __builtin_amdgcn_exp2f(x)
#  endif
#endif
#ifndef EXP2
#  define EXP2(x) exp2f(x)
#endif

typedef __attribute__((ext_vector_type(8))) short short8_t;
typedef __attribute__((ext_vector_type(4))) float f32x4;

__device__ __forceinline__ short f2bf(float f) {
    __bf16 h = (__bf16)f;
    return __builtin_bit_cast(short, h);
}

#define PADK 72   // bf16 row stride for MFMA staging tiles (144 B)

// Stage one e-group (4 e's) of lig[16 l] and rec[16 r] slices as bf16.
__device__ __forceinline__ void stage_group(const float* __restrict__ lig,
                                            const float* __restrict__ rec,
                                            int l0, int r0, int g,
                                            short* __restrict__ ligbuf,
                                            short* __restrict__ recbuf,
                                            int tid) {
#pragma unroll
    for (int i = 0; i < 4; ++i) {              // lig: 4e x 16l x 16 float4
        int idx = i * 256 + tid;
        int eg  = idx >> 8;
        int row = (idx >> 4) & 15;
        int f4  = idx & 15;
        float4 v = *(const float4*)(lig + ((size_t)(l0 + row) * 32 + (4 * g + eg)) * 64 + f4 * 4);
        short4 p;
        p.x = f2bf(v.x); p.y = f2bf(v.y); p.z = f2bf(v.z); p.w = f2bf(v.w);
        *(short4*)(&ligbuf[eg * (16 * PADK) + row * PADK + f4 * 4]) = p;
    }
#pragma unroll
    for (int i = 0; i < 4; ++i) {              // rec: 4e x 16r x 16 float4
        int idx = i * 256 + tid;
        int eg  = idx >> 8;
        int row = (idx >> 4) & 15;
        int f4  = idx & 15;
        float4 v = *(const float4*)(rec + ((size_t)(r0 + row) * 32 + (4 * g + eg)) * 64 + f4 * 4);
        short4 p;
        p.x = f2bf(v.x); p.y = f2bf(v.y); p.z = f2bf(v.z); p.w = f2bf(v.w);
        *(short4*)(&recbuf[eg * (16 * PADK) + row * PADK + f4 * 4]) = p;
    }
}

// ---------------------------------------------------------------------------
// Fused kernel: block = 16 l x 16 r tile, only the needed e-groups.
// Phase 0: distances d[t] per pair -> block-uniform [gmin, gmax] e-groups.
// Phase 1: atn tile [e][16 l][16 r] (bf16) via MFMA into LDS, groups
//          gmin..gmax only (double-buffered staging; one e per wave).
// Phase 2: acc[t] += atn * exp2(-(d*SFAC - e*MUS)^2), 5-wide window around
//          e0 (within staged range by construction); reduce -> partials.
// Grid 512 blocks (8 lt x 64 rt), 256 threads = 4 waves, 2 blocks/CU.
// ---------------------------------------------------------------------------
__global__ __launch_bounds__(256) void fused_kernel(const float* __restrict__ lig,
                                                    const float* __restrict__ rec,
                                                    const float* __restrict__ ligc,
                                                    const float* __restrict__ recc,
                                                    float* __restrict__ partials) {
    const int tid = threadIdx.x;
    const int lt  = blockIdx.x >> 6;     // 0..7
    const int rtc = blockIdx.x & 63;     // 0..63
    const int l0  = lt * 16;
    const int r0  = rtc * 16;

    __shared__ short atn_s[E_CNT * 16 * 16];                 // e*256 + l*16 + r, 16 KB
    __shared__ __align__(16) short lig_s[2][4 * 16 * PADK];  // 18432 B
    __shared__ __align__(16) short rec_s[2][4 * 16 * PADK];  // 18432 B
    __shared__ float ligc_s[T_CNT * 16 * 3];                 // [t][l][xyz], 3 KB
    __shared__ float red[4][T_CNT];
    __shared__ int grange_s[8];                              // [wave]=gmax, [4+wave]=gmin

    // stage ligc tile: 768 floats
#pragma unroll
    for (int i = 0; i < 3; ++i) {
        int idx = i * 256 + tid;         // t*48 + (l*3+c)
        int t   = idx / 48;
        int rem = idx - t * 48;
        ligc_s[idx] = ligc[(size_t)t * 384 + l0 * 3 + rem];
    }

    const int wave = tid >> 6;
    const int lane = tid & 63;
    const int fr   = lane & 15;
    const int kg   = lane >> 4;

    // ---- Phase 0: distances + block-uniform e-group range ----
    const int l_loc = tid >> 4;
    const int r_loc = tid & 15;
    const int r_g   = r0 + r_loc;

    const float rx = recc[r_g * 3 + 0];
    const float ry = recc[r_g * 3 + 1];
    const float rz = recc[r_g * 3 + 2];

    __syncthreads();                      // ligc_s ready

    float d[T_CNT];
    float e0max = 2.0f;
    float e0min = 29.0f;
#pragma unroll
    for (int t = 0; t < T_CNT; ++t) {
        float dx = ligc_s[t * 48 + l_loc * 3 + 0] - rx;
        float dy = ligc_s[t * 48 + l_loc * 3 + 1] - ry;
        float dz = ligc_s[t * 48 + l_loc * 3 + 2] - rz;
        d[t] = sqrtf(dx * dx + dy * dy + dz * dz);
        float e0f = rintf(d[t] * SFAC * INV_MUS);
        e0f = fminf(fmaxf(e0f, 2.0f), 29.0f);   // same clamp as phase 2
        e0max = fmaxf(e0max, e0f);
        e0min = fminf(e0min, e0f);
    }
    // wave reduce, then cross-wave
#pragma unroll
    for (int m = 32; m >= 1; m >>= 1) {
        e0max = fmaxf(e0max, __shfl_xor(e0max, m, 64));
        e0min = fminf(e0min, __shfl_xor(e0min, m, 64));
    }
    if (lane == 0) {
        grange_s[wave]     = ((int)e0max + 2) >> 2;   // highest needed group
        grange_s[4 + wave] = ((int)e0min - 2) >> 2;   // lowest needed group
    }
    __syncthreads();
    const int gmax = max(max(grange_s[0], grange_s[1]), max(grange_s[2], grange_s[3]));
    const int gmin = min(min(grange_s[4], grange_s[5]), min(grange_s[6], grange_s[7]));

    // ---- Phase 1: GEMM into LDS, e-groups gmin..gmax, double-buffered ----
    stage_group(lig, rec, l0, r0, gmin, lig_s[gmin & 1], rec_s[gmin & 1], tid);
    __syncthreads();

    for (int g = gmin; g <= gmax; ++g) {
        if (g < gmax) stage_group(lig, rec, l0, r0, g + 1, lig_s[(g + 1) & 1], rec_s[(g + 1) & 1], tid);

        // compute e = 4g + wave from buffer g&1
        const short* A = &lig_s[g & 1][wave * (16 * PADK)];
        const short* B = &rec_s[g & 1][wave * (16 * PADK)];
        short8_t a0 = *(const short8_t*)(A + fr * PADK + kg * 8);
        short8_t a1 = *(const short8_t*)(A + fr * PADK + 32 + kg * 8);
        short8_t b0 = *(const short8_t*)(B + fr * PADK + kg * 8);
        short8_t b1 = *(const short8_t*)(B + fr * PADK + 32 + kg * 8);
        f32x4 c = (f32x4){0.f, 0.f, 0.f, 0.f};
        c = __builtin_amdgcn_mfma_f32_16x16x32_bf16(a0, b0, c, 0, 0, 0);
        c = __builtin_amdgcn_mfma_f32_16x16x32_bf16(a1, b1, c, 0, 0, 0);

        // C/D layout: col(r) = lane&15, row(l) = (lane>>4)*4 + j
        const int e    = 4 * g + wave;
        const int rowb = (lane >> 4) * 4;
#pragma unroll
        for (int j = 0; j < 4; ++j) {
            atn_s[e * 256 + (rowb + j) * 16 + fr] = f2bf(c[j]);
        }
        __syncthreads();
    }

    // ---- Phase 2: energy. 1 pair/thread (same l_loc/r_loc as phase 0) ----
    float acc[T_CNT];
#pragma unroll
    for (int t = 0; t < T_CNT; ++t) acc[t] = 0.0f;

    const int pbase = l_loc * 16 + r_loc;
#pragma unroll
    for (int t = 0; t < T_CNT; ++t) {
        const float u = d[t] * SFAC;
        float e0f = rintf(u * INV_MUS);
        e0f = fminf(fmaxf(e0f, 2.0f), 29.0f);   // window [e0-2, e0+2] in [0,31]
        const int   em2 = (int)e0f - 2;
        const float um  = fmaf(e0f, -MUS, u);
#pragma unroll
        for (int k = 0; k < 5; ++k) {
            const float w  = um - (float)(k - 2) * MUS;
            const float ae = __uint_as_float(
                (unsigned)(unsigned short)atn_s[(em2 + k) * 256 + pbase] << 16);
            acc[t] = fmaf(ae, EXP2(-(w * w)), acc[t]);
        }
    }

    // Block reduction: shuffle within wave, then LDS across 4 waves.
#pragma unroll
    for (int t = 0; t < T_CNT; ++t) {
#pragma unroll
        for (int m = 32; m >= 1; m >>= 1) acc[t] += __shfl_xor(acc[t], m, 64);
    }
    if (lane == 0) {
#pragma unroll
        for (int t = 0; t < T_CNT; ++t) red[wave][t] = acc[t];
    }
    __syncthreads();
    if (tid < T_CNT) {
        float s = red[0][tid] + red[1][tid] + red[2][tid] + red[3][tid];
        partials[(size_t)blockIdx.x * T_CNT + tid] = s;
    }
}

// ---------------------------------------------------------------------------
// Deterministic final reduce of 512 x 16 partials -> out[16]
// ---------------------------------------------------------------------------
__global__ __launch_bounds__(256) void final_reduce(const float* __restrict__ partials,
                                                    float* __restrict__ out) {
    __shared__ float red[16][17];
    const int t = threadIdx.x & 15;
    const int g = threadIdx.x >> 4;
    float s = 0.0f;
    for (int b = g; b < 512; b += 16) s += partials[(size_t)b * 16 + t];
    red[g][t] = s;
    __syncthreads();
    if (threadIdx.x < 16) {
        float v = 0.0f;
#pragma unroll
        for (int g2 = 0; g2 < 16; ++g2) v += red[g2][threadIdx.x];
        out[threadIdx.x] = v;
    }
}

extern "C" void kernel_launch(void* const* d_in, const int* in_sizes, int n_in,
                              void* d_out, int out_size, void* d_ws, size_t ws_size,
                              hipStream_t stream) {
    const float* lig  = (const float*)d_in[0];   // [128,32,64]
    const float* rec  = (const float*)d_in[1];   // [1024,32,64]
    const float* ligc = (const float*)d_in[2];   // [16,128,3]
    const float* recc = (const float*)d_in[3];   // [1024,3]
    float* out = (float*)d_out;                  // [16]

    float* partials = (float*)d_ws;              // 512*16 floats

    fused_kernel<<<512, 256, 0, stream>>>(lig, rec, ligc, recc, partials);
    final_reduce<<<1, 256, 0, stream>>>(partials, out);
}